// Round 3
// baseline (1584.876 us; speedup 1.0000x reference)
//
#include <hip/hip_runtime.h>
#include <float.h>
#include <math.h>

// Problem constants (fixed by the reference: N=8192, D=512, k+1=31).
#define NN 8192
#define DD 512
#define TOPK 31

// Faithful fp32 emulation of the numpy reference pipeline:
//   h = relu(f*W1)*W2            (elementwise fp32; exact for W=ones)
//   n = sqrtf(pairwise_sum(h*h)) (numpy pairwise: 512 -> (B0+B1)+(B2+B3),
//                                 base-128 = 8 SIMD accs + stride-halving reduce)
//   e = h / n                    (IEEE fp32 divide)
//   sim[i][j] = sequential-k fp32 FMA chain over e_i*e_j (OpenBLAS-style)
//   top-31 per row on those fp32 values, ties -> lower index (stable top_k)

__device__ __forceinline__ float h_elem(const float* __restrict__ f,
                                        const float* __restrict__ W1,
                                        const float* __restrict__ W2, int k) {
  float x = f[k] * W1[k];
  x = fmaxf(x, 0.0f);
  return x * W2[k];
}

// ---------------------------------------------------------------------------
// Kernel A: per-row fp32 norm with numpy's pairwise-summation association.
// ---------------------------------------------------------------------------
__global__ __launch_bounds__(256) void norm_kernel(
    const float* __restrict__ f, const float* __restrict__ W1,
    const float* __restrict__ W2, float* __restrict__ n32) {
  const int row = blockIdx.x * 256 + threadIdx.x;
  if (row >= NN) return;
  const float* fr = f + (size_t)row * DD;

  float nb[4];
#pragma unroll
  for (int b = 0; b < 4; ++b) {
    float v[16];
#pragma unroll
    for (int L = 0; L < 16; ++L) {
      const int base = b * 128 + L;
      float h, s0, s1, s2, s3, s4, s5, s6, s7;
      h = h_elem(fr, W1, W2, base + 0);   s0 = h * h;
      h = h_elem(fr, W1, W2, base + 16);  s1 = h * h;
      h = h_elem(fr, W1, W2, base + 32);  s2 = h * h;
      h = h_elem(fr, W1, W2, base + 48);  s3 = h * h;
      h = h_elem(fr, W1, W2, base + 64);  s4 = h * h;
      h = h_elem(fr, W1, W2, base + 80);  s5 = h * h;
      h = h_elem(fr, W1, W2, base + 96);  s6 = h * h;
      h = h_elem(fr, W1, W2, base + 112); s7 = h * h;
      v[L] = ((s0 + s1) + (s2 + s3)) + ((s4 + s5) + (s6 + s7));
    }
    float t1[8];
#pragma unroll
    for (int L = 0; L < 8; ++L) t1[L] = v[L] + v[L + 8];
    float t2[4];
#pragma unroll
    for (int L = 0; L < 4; ++L) t2[L] = t1[L] + t1[L + 4];
    float t3a = t2[0] + t2[2];
    float t3b = t2[1] + t2[3];
    nb[b] = t3a + t3b;
  }
  float norm2 = (nb[0] + nb[1]) + (nb[2] + nb[3]);
  n32[row] = fmaxf(sqrtf(norm2), 1e-12f);
}

// ---------------------------------------------------------------------------
// Kernel B: e32[j][k] = h / n  (IEEE fp32 divide), coalesced.
// ---------------------------------------------------------------------------
__global__ __launch_bounds__(256) void e32_kernel(
    const float* __restrict__ f, const float* __restrict__ W1,
    const float* __restrict__ W2, const float* __restrict__ n32,
    float* __restrict__ e32) {
  const int row = blockIdx.x;
  const float n = n32[row];
  const float* fr = f + (size_t)row * DD;
  float* er = e32 + (size_t)row * DD;
  for (int k = threadIdx.x; k < DD; k += 256) {
    er[k] = h_elem(fr, W1, W2, k) / n;
  }
}

// ---------------------------------------------------------------------------
// Kernel C: C = E * E^T, fp32, 64x64 tile, 4x4/thread. Each C element is a
// single sequential-k fmaf chain (k ascending 0..511) — OpenBLAS-like.
// ---------------------------------------------------------------------------
#define BT 64
#define KC 16

__global__ __launch_bounds__(256) void sim_kernel(
    const float* __restrict__ E, float* __restrict__ C) {
  __shared__ __align__(16) float As[KC][BT + 4];
  __shared__ __align__(16) float Bs[KC][BT + 4];
  const int tx = threadIdx.x & 15;
  const int ty = threadIdx.x >> 4;
  const int i0 = blockIdx.y * BT;
  const int j0 = blockIdx.x * BT;
  const int lr = threadIdx.x >> 2;
  const int lc = (threadIdx.x & 3) << 2;

  float acc[4][4];
#pragma unroll
  for (int r = 0; r < 4; ++r)
#pragma unroll
    for (int c = 0; c < 4; ++c) acc[r][c] = 0.f;

  for (int kk = 0; kk < DD; kk += KC) {
    float4 av = *(const float4*)(E + (size_t)(i0 + lr) * DD + kk + lc);
    float4 bv = *(const float4*)(E + (size_t)(j0 + lr) * DD + kk + lc);
    As[lc + 0][lr] = av.x; As[lc + 1][lr] = av.y;
    As[lc + 2][lr] = av.z; As[lc + 3][lr] = av.w;
    Bs[lc + 0][lr] = bv.x; Bs[lc + 1][lr] = bv.y;
    Bs[lc + 2][lr] = bv.z; Bs[lc + 3][lr] = bv.w;
    __syncthreads();
#pragma unroll
    for (int k2 = 0; k2 < KC; ++k2) {
      float4 a = *(const float4*)&As[k2][ty << 2];
      float4 b = *(const float4*)&Bs[k2][tx << 2];
      acc[0][0] = fmaf(a.x, b.x, acc[0][0]);
      acc[0][1] = fmaf(a.x, b.y, acc[0][1]);
      acc[0][2] = fmaf(a.x, b.z, acc[0][2]);
      acc[0][3] = fmaf(a.x, b.w, acc[0][3]);
      acc[1][0] = fmaf(a.y, b.x, acc[1][0]);
      acc[1][1] = fmaf(a.y, b.y, acc[1][1]);
      acc[1][2] = fmaf(a.y, b.z, acc[1][2]);
      acc[1][3] = fmaf(a.y, b.w, acc[1][3]);
      acc[2][0] = fmaf(a.z, b.x, acc[2][0]);
      acc[2][1] = fmaf(a.z, b.y, acc[2][1]);
      acc[2][2] = fmaf(a.z, b.z, acc[2][2]);
      acc[2][3] = fmaf(a.z, b.w, acc[2][3]);
      acc[3][0] = fmaf(a.w, b.x, acc[3][0]);
      acc[3][1] = fmaf(a.w, b.y, acc[3][1]);
      acc[3][2] = fmaf(a.w, b.z, acc[3][2]);
      acc[3][3] = fmaf(a.w, b.w, acc[3][3]);
    }
    __syncthreads();
  }
#pragma unroll
  for (int r = 0; r < 4; ++r) {
    float4 v = make_float4(acc[r][0], acc[r][1], acc[r][2], acc[r][3]);
    *(float4*)(C + (size_t)(i0 + (ty << 2) + r) * NN + j0 + (tx << 2)) = v;
  }
}

// ---------------------------------------------------------------------------
// Kernel D: per-row top-31 directly on the fp32 sim values (ties -> lower
// index, matching stable top_k); write relu(value) at kept indices, 0 else.
// ---------------------------------------------------------------------------
__global__ __launch_bounds__(256) void topk_kernel(float* __restrict__ C) {
  const int row = blockIdx.x;
  const int tid = threadIdx.x;
  const int lane = tid & 63, wid = tid >> 6;

  __shared__ float sv[NN];  // 32 KB
  __shared__ unsigned long long kred[4];
  __shared__ int kidx[TOPK];
  __shared__ float kval[TOPK];

  float* Crow = C + (size_t)row * NN;
  for (int j = tid; j < NN; j += 256) sv[j] = Crow[j];
  __syncthreads();

  for (int it = 0; it < TOPK; ++it) {
    float bv = -FLT_MAX;
    int bi = 0;
    for (int j = tid; j < NN; j += 256) {
      float v = sv[j];
      if (v > bv) { bv = v; bi = j; }
    }
    unsigned int u = __float_as_uint(bv);
    u = (u & 0x80000000u) ? ~u : (u | 0x80000000u);
    unsigned long long key =
        ((unsigned long long)u << 32) | (unsigned int)(NN - 1 - bi);
#pragma unroll
    for (int off = 32; off; off >>= 1) {
      unsigned long long o = __shfl_down(key, off);
      if (o > key) key = o;
    }
    if (lane == 0) kred[wid] = key;
    __syncthreads();
    if (tid == 0) {
      unsigned long long k0 = kred[0];
      if (kred[1] > k0) k0 = kred[1];
      if (kred[2] > k0) k0 = kred[2];
      if (kred[3] > k0) k0 = kred[3];
      int idx = (NN - 1) - (int)(k0 & 0xFFFFFFFFu);
      kidx[it] = idx;
      kval[it] = sv[idx];
      sv[idx] = -FLT_MAX;
    }
    __syncthreads();
  }

  for (int j = tid; j < NN; j += 256) sv[j] = 0.0f;
  __syncthreads();
  if (tid < TOPK) sv[kidx[tid]] = fmaxf(kval[tid], 0.0f);
  __syncthreads();
  for (int j = tid; j < NN; j += 256) Crow[j] = sv[j];
}

// ---------------------------------------------------------------------------
extern "C" void kernel_launch(void* const* d_in, const int* in_sizes, int n_in,
                              void* d_out, int out_size, void* d_ws,
                              size_t ws_size, hipStream_t stream) {
  const float* f = (const float*)d_in[0];
  const float* W1 = (const float*)d_in[1];
  const float* W2 = (const float*)d_in[2];
  float* out = (float*)d_out;
  float* n32 = (float*)d_ws;        // 8192 fp32 = 32 KB
  float* e32 = (float*)d_ws + NN;   // 8192*512 fp32 = 16 MiB

  norm_kernel<<<NN / 256, 256, 0, stream>>>(f, W1, W2, n32);
  e32_kernel<<<NN, 256, 0, stream>>>(f, W1, W2, n32, e32);
  dim3 g2(NN / BT, NN / BT);
  sim_kernel<<<g2, 256, 0, stream>>>(e32, out);
  topk_kernel<<<NN, 256, 0, stream>>>(out);
}

// Round 4
// 949.101 us; speedup vs baseline: 1.6699x; 1.6699x over previous
//
#include <hip/hip_runtime.h>
#include <float.h>
#include <math.h>

// Problem constants (fixed by the reference: N=8192, D=512, k+1=31).
#define NN 8192
#define DD 512
#define TOPK 31
#define CAP 1024  // candidate cap for threshold-collect (typical count ~35)

// Bit-exact fp32 emulation of the numpy reference (absmax 0.0 in R3):
//   h = relu(f*W1)*W2                      (elementwise fp32)
//   n = sqrtf(numpy-pairwise sum of h*h)   (8x16-lane SIMD assoc, verified)
//   e = h / n                              (IEEE fp32 divide)
//   sim[i][j] = sequential-k fmaf chain    (OpenBLAS-like)
//   top-31 per row, ties -> lower index    (stable top_k)
// R4: symmetric GEMM (mirror is bit-exact by fp-mul commutativity),
//     8x8/thread 128-tiles, threshold-based top-k, fused norm+divide.

__device__ __forceinline__ float h_elem(const float* __restrict__ f,
                                        const float* __restrict__ W1,
                                        const float* __restrict__ W2, int k) {
  float x = f[k] * W1[k];
  x = fmaxf(x, 0.0f);
  return x * W2[k];
}

// ---------------------------------------------------------------------------
// Kernel A: fused norm (numpy pairwise association) + e = h/n.
// One wave per row; shuffle tree reproduces the exact fp32 association:
//   v[L] = ((s0+s1)+(s2+s3))+((s4+s5)+(s6+s7)), s_j = h[b*128+16j+L]^2
//   nb[b] via stride-halving (8,4,2,1); norm2 = (nb0+nb1)+(nb2+nb3)
// (xor-shuffle partners give commuted-operand sums == bit-identical.)
// ---------------------------------------------------------------------------
__global__ __launch_bounds__(256) void emb_kernel(
    const float* __restrict__ f, const float* __restrict__ W1,
    const float* __restrict__ W2, float* __restrict__ e32) {
  const int lane = threadIdx.x & 63;
  const int row = blockIdx.x * 4 + (threadIdx.x >> 6);
  const float* fr = f + (size_t)row * DD;
  const int b = lane >> 4, L = lane & 15;

  float s[8];
#pragma unroll
  for (int j = 0; j < 8; ++j) {
    float h = h_elem(fr, W1, W2, b * 128 + 16 * j + L);
    s[j] = h * h;
  }
  float v = ((s[0] + s[1]) + (s[2] + s[3])) + ((s[4] + s[5]) + (s[6] + s[7]));
  float t = v + __shfl_xor(v, 8);
  t = t + __shfl_xor(t, 4);
  t = t + __shfl_xor(t, 2);
  float nb = t + __shfl_xor(t, 1);        // nb[b] on every lane of group b
  float x = nb + __shfl_xor(nb, 16);      // nb0+nb1 / nb2+nb3
  float norm2 = x + __shfl_xor(x, 32);    // (nb0+nb1)+(nb2+nb3)
  const float n = fmaxf(sqrtf(norm2), 1e-12f);

  float* er = e32 + (size_t)row * DD;
#pragma unroll
  for (int m = 0; m < 8; ++m) {
    int k = m * 64 + lane;
    er[k] = h_elem(fr, W1, W2, k) / n;
  }
}

// ---------------------------------------------------------------------------
// Kernel B: C = E*E^T, fp32, symmetric. 128x128 tile, 256 thr, 8x8/thread
// (2x2 sub-tiles of 4x4 at offsets {0,64} -> only free 2-way LDS conflicts).
// Each C element is one sequential-k fmaf chain (bit-exact). Off-diagonal
// blocks also write the mirrored tile (commutativity => bit-identical).
// ---------------------------------------------------------------------------
#define BT 128
#define KC 16

__global__ __launch_bounds__(256) void sim_kernel(
    const float* __restrict__ E, float* __restrict__ C) {
  const int bx = blockIdx.x, by = blockIdx.y;
  if (bx < by) return;  // upper-triangular blocks only

  __shared__ __align__(16) float As[KC][BT + 4];
  __shared__ __align__(16) float Bs[KC][BT + 4];
  const int t = threadIdx.x;
  const int tx = t & 15, ty = t >> 4;
  const int i0 = by * BT, j0 = bx * BT;
  const int lr = t >> 1;        // 0..127: staged row
  const int lk = (t & 1) * 8;   // 0 or 8: staged k-offset

  float acc[2][2][4][4];
#pragma unroll
  for (int a = 0; a < 2; ++a)
#pragma unroll
    for (int b = 0; b < 2; ++b)
#pragma unroll
      for (int r = 0; r < 4; ++r)
#pragma unroll
        for (int c = 0; c < 4; ++c) acc[a][b][r][c] = 0.f;

  const float* Arow = E + (size_t)(i0 + lr) * DD + lk;
  const float* Brow = E + (size_t)(j0 + lr) * DD + lk;

  for (int kk = 0; kk < DD; kk += KC) {
    float4 a0 = *(const float4*)(Arow + kk);
    float4 a1 = *(const float4*)(Arow + kk + 4);
    float4 b0 = *(const float4*)(Brow + kk);
    float4 b1 = *(const float4*)(Brow + kk + 4);
    As[lk + 0][lr] = a0.x; As[lk + 1][lr] = a0.y;
    As[lk + 2][lr] = a0.z; As[lk + 3][lr] = a0.w;
    As[lk + 4][lr] = a1.x; As[lk + 5][lr] = a1.y;
    As[lk + 6][lr] = a1.z; As[lk + 7][lr] = a1.w;
    Bs[lk + 0][lr] = b0.x; Bs[lk + 1][lr] = b0.y;
    Bs[lk + 2][lr] = b0.z; Bs[lk + 3][lr] = b0.w;
    Bs[lk + 4][lr] = b1.x; Bs[lk + 5][lr] = b1.y;
    Bs[lk + 6][lr] = b1.z; Bs[lk + 7][lr] = b1.w;
    __syncthreads();
#pragma unroll
    for (int k2 = 0; k2 < KC; ++k2) {
      float4 A0 = *(const float4*)&As[k2][ty * 4];
      float4 A1 = *(const float4*)&As[k2][64 + ty * 4];
      float4 B0 = *(const float4*)&Bs[k2][tx * 4];
      float4 B1 = *(const float4*)&Bs[k2][64 + tx * 4];
      float ar[2][4] = {{A0.x, A0.y, A0.z, A0.w}, {A1.x, A1.y, A1.z, A1.w}};
      float br[2][4] = {{B0.x, B0.y, B0.z, B0.w}, {B1.x, B1.y, B1.z, B1.w}};
#pragma unroll
      for (int rb = 0; rb < 2; ++rb)
#pragma unroll
        for (int cb = 0; cb < 2; ++cb)
#pragma unroll
          for (int r = 0; r < 4; ++r)
#pragma unroll
            for (int c = 0; c < 4; ++c)
              acc[rb][cb][r][c] = fmaf(ar[rb][r], br[cb][c], acc[rb][cb][r][c]);
    }
    __syncthreads();
  }

  // normal write: rows i0+rb*64+ty*4+r, cols j0+{0,64}+tx*4
#pragma unroll
  for (int rb = 0; rb < 2; ++rb)
#pragma unroll
    for (int r = 0; r < 4; ++r) {
      float* Cr = C + (size_t)(i0 + rb * 64 + ty * 4 + r) * NN + j0;
      *(float4*)(Cr + tx * 4) =
          make_float4(acc[rb][0][r][0], acc[rb][0][r][1], acc[rb][0][r][2], acc[rb][0][r][3]);
      *(float4*)(Cr + 64 + tx * 4) =
          make_float4(acc[rb][1][r][0], acc[rb][1][r][1], acc[rb][1][r][2], acc[rb][1][r][3]);
    }

  if (bx > by) {  // mirror write: rows j0+cb*64+tx*4+c, cols i0+{0,64}+ty*4
#pragma unroll
    for (int cb = 0; cb < 2; ++cb)
#pragma unroll
      for (int c = 0; c < 4; ++c) {
        float* Cr = C + (size_t)(j0 + cb * 64 + tx * 4 + c) * NN + i0;
        *(float4*)(Cr + ty * 4) =
            make_float4(acc[0][cb][0][c], acc[0][cb][1][c], acc[0][cb][2][c], acc[0][cb][3][c]);
        *(float4*)(Cr + 64 + ty * 4) =
            make_float4(acc[1][cb][0][c], acc[1][cb][1][c], acc[1][cb][2][c], acc[1][cb][3][c]);
      }
  }
}

// ---------------------------------------------------------------------------
// Kernel C: per-row top-31 via threshold select.
//  1) per-thread max over strided slice (1 scan)
//  2) 31 arg-max rounds over the 256 register maxima -> T = 31st largest
//     (each winner is a distinct row element => #{v >= T} >= 31 guaranteed)
//  3) collect indices with v >= T (typically ~35; cap 1024 w/ exact fallback)
//  4) exact rank by (value desc, index asc) -> stable top-31
//  5) write zeros + relu(kept values)
// ---------------------------------------------------------------------------
__global__ __launch_bounds__(256) void topk_kernel(float* __restrict__ C) {
  const int row = blockIdx.x;
  const int tid = threadIdx.x;
  const int lane = tid & 63, wid = tid >> 6;

  __shared__ float sv[NN];  // 32 KB
  __shared__ unsigned long long wred[4];
  __shared__ int cand[CAP];
  __shared__ int s_cnt;
  __shared__ int kidx[TOPK];
  __shared__ float kval[TOPK];

  float* Crow = C + (size_t)row * NN;
  float4* sv4 = (float4*)sv;
  const float4* Cr4 = (const float4*)Crow;
  for (int i = tid; i < NN / 4; i += 256) sv4[i] = Cr4[i];
  if (tid == 0) s_cnt = 0;
  __syncthreads();

  float myv = -FLT_MAX;
  for (int j = tid; j < NN; j += 256) {
    float v = sv[j];
    if (v > myv) myv = v;
  }

  float T = 0.f;
  for (int it = 0; it < TOPK; ++it) {
    unsigned int u = __float_as_uint(myv);
    u = (u & 0x80000000u) ? ~u : (u | 0x80000000u);
    unsigned long long key =
        ((unsigned long long)u << 32) | (unsigned int)(255 - tid);
#pragma unroll
    for (int off = 32; off; off >>= 1) {
      unsigned long long o = __shfl_xor(key, off);
      if (o > key) key = o;
    }
    if (lane == 0) wred[wid] = key;
    __syncthreads();
    unsigned long long k0 = wred[0];
    if (wred[1] > k0) k0 = wred[1];
    if (wred[2] > k0) k0 = wred[2];
    if (wred[3] > k0) k0 = wred[3];
    if (it == TOPK - 1) {
      unsigned int uu = (unsigned int)(k0 >> 32);
      uu = (uu & 0x80000000u) ? (uu & 0x7fffffffu) : ~uu;  // inverse map
      T = __uint_as_float(uu);
    }
    if (tid == (int)(255u - (unsigned int)(k0 & 0xFFu))) myv = -FLT_MAX;
    __syncthreads();
  }

  for (int j = tid; j < NN; j += 256) {
    if (sv[j] >= T) {
      int p = atomicAdd(&s_cnt, 1);
      if (p < CAP) cand[p] = j;
    }
  }
  __syncthreads();
  const int cnt = s_cnt;

  if (cnt <= CAP) {
    for (int c = tid; c < cnt; c += 256) {
      int idx = cand[c];
      float v = sv[idx];
      int rank = 0;
      for (int c2 = 0; c2 < cnt; ++c2) {
        int idx2 = cand[c2];
        float v2 = sv[idx2];
        if (v2 > v || (v2 == v && idx2 < idx)) ++rank;
      }
      if (rank < TOPK) { kidx[rank] = idx; kval[rank] = v; }
    }
    __syncthreads();
  } else {
    // exact fallback (statistically never taken): 31 full-row argmax rounds
    for (int it = 0; it < TOPK; ++it) {
      float bv = -FLT_MAX;
      int bi = 0;
      for (int j = tid; j < NN; j += 256) {
        float v = sv[j];
        if (v > bv) { bv = v; bi = j; }
      }
      unsigned int u = __float_as_uint(bv);
      u = (u & 0x80000000u) ? ~u : (u | 0x80000000u);
      unsigned long long key =
          ((unsigned long long)u << 32) | (unsigned int)(NN - 1 - bi);
#pragma unroll
      for (int off = 32; off; off >>= 1) {
        unsigned long long o = __shfl_xor(key, off);
        if (o > key) key = o;
      }
      if (lane == 0) wred[wid] = key;
      __syncthreads();
      if (tid == 0) {
        unsigned long long k0 = wred[0];
        if (wred[1] > k0) k0 = wred[1];
        if (wred[2] > k0) k0 = wred[2];
        if (wred[3] > k0) k0 = wred[3];
        int idx = (NN - 1) - (int)(k0 & 0xFFFFFFFFu);
        kidx[it] = idx;
        kval[it] = sv[idx];
        sv[idx] = -FLT_MAX;
      }
      __syncthreads();
    }
  }

  float4 z4 = make_float4(0.f, 0.f, 0.f, 0.f);
  for (int i = tid; i < NN / 4; i += 256) sv4[i] = z4;
  __syncthreads();
  if (tid < TOPK) sv[kidx[tid]] = fmaxf(kval[tid], 0.0f);
  __syncthreads();
  float4* Cw4 = (float4*)Crow;
  for (int i = tid; i < NN / 4; i += 256) Cw4[i] = sv4[i];
}

// ---------------------------------------------------------------------------
extern "C" void kernel_launch(void* const* d_in, const int* in_sizes, int n_in,
                              void* d_out, int out_size, void* d_ws,
                              size_t ws_size, hipStream_t stream) {
  const float* f = (const float*)d_in[0];
  const float* W1 = (const float*)d_in[1];
  const float* W2 = (const float*)d_in[2];
  float* out = (float*)d_out;
  float* e32 = (float*)d_ws;  // 8192*512 fp32 = 16 MiB

  emb_kernel<<<NN / 4, 256, 0, stream>>>(f, W1, W2, e32);
  dim3 g2(NN / BT, NN / BT);
  sim_kernel<<<g2, 256, 0, stream>>>(e32, out);
  topk_kernel<<<NN, 256, 0, stream>>>(out);
}

// Round 5
// 933.965 us; speedup vs baseline: 1.6969x; 1.0162x over previous
//
#include <hip/hip_runtime.h>
#include <float.h>
#include <math.h>

// Problem constants (fixed by the reference: N=8192, D=512, k+1=31).
#define NN 8192
#define DD 512
#define TOPK 31
#define CAP 2048          // candidate cap (typical cnt ~32; fallback if exceeded)
#define DELTA 1e-4f       // >= 5x the guaranteed |approx-exact| bound (~2e-5)

// Strategy (R5):
//   Values chain (bit-exact vs np ref, absmax 0.0 since R3):
//     h = relu(f*W1)*W2 ; n = sqrtf(numpy-pairwise sum h*h) ; e = h/n
//     sim[i][j] = sequential-k fmaf chain over e_i*e_j
//   Speed: sim is computed APPROXIMATELY with bf16 MFMA (e = hi + lo split,
//   acc = hi*hi + hi*lo + lo*hi, upper-triangle tiles only, mirrored by a
//   transpose kernel). The top-k kernel collects candidates with a margin
//   around the approx 31st value, recomputes the EXACT fp32 chain for each
//   candidate from e32, and selects/writes by exact value (ties -> lower idx).

typedef __attribute__((ext_vector_type(8))) short short8;
typedef __attribute__((ext_vector_type(4))) float f32x4;

__device__ __forceinline__ float h_elem(const float* __restrict__ f,
                                        const float* __restrict__ W1,
                                        const float* __restrict__ W2, int k) {
  float x = f[k] * W1[k];
  x = fmaxf(x, 0.0f);
  return x * W2[k];
}

__device__ __forceinline__ unsigned short f2bf_rne(float x) {
  unsigned u = __float_as_uint(x);
  unsigned r = (u >> 16) & 1u;
  u += 0x7fffu + r;
  return (unsigned short)(u >> 16);
}
__device__ __forceinline__ float bf2f(unsigned short h) {
  return __uint_as_float(((unsigned)h) << 16);
}

// ---------------------------------------------------------------------------
// Kernel A: fused norm (numpy pairwise association, bit-exact) + e = h/n,
// plus bf16 hi/lo split of e for the MFMA path. One wave per row.
// ---------------------------------------------------------------------------
__global__ __launch_bounds__(256) void emb_kernel(
    const float* __restrict__ f, const float* __restrict__ W1,
    const float* __restrict__ W2, float* __restrict__ e32,
    unsigned short* __restrict__ Ehi, unsigned short* __restrict__ Elo) {
  const int lane = threadIdx.x & 63;
  const int row = blockIdx.x * 4 + (threadIdx.x >> 6);
  const float* fr = f + (size_t)row * DD;
  const int b = lane >> 4, L = lane & 15;

  float s[8];
#pragma unroll
  for (int j = 0; j < 8; ++j) {
    float h = h_elem(fr, W1, W2, b * 128 + 16 * j + L);
    s[j] = h * h;
  }
  float v = ((s[0] + s[1]) + (s[2] + s[3])) + ((s[4] + s[5]) + (s[6] + s[7]));
  float t = v + __shfl_xor(v, 8);
  t = t + __shfl_xor(t, 4);
  t = t + __shfl_xor(t, 2);
  float nb = t + __shfl_xor(t, 1);
  float x = nb + __shfl_xor(nb, 16);
  float norm2 = x + __shfl_xor(x, 32);
  const float n = fmaxf(sqrtf(norm2), 1e-12f);

  float* er = e32 + (size_t)row * DD;
  unsigned short* hr = Ehi + (size_t)row * DD;
  unsigned short* lr = Elo + (size_t)row * DD;
#pragma unroll
  for (int m = 0; m < 8; ++m) {
    int k = m * 64 + lane;
    float e = h_elem(fr, W1, W2, k) / n;
    er[k] = e;
    unsigned short hb = f2bf_rne(e);
    hr[k] = hb;
    lr[k] = f2bf_rne(e - bf2f(hb));
  }
}

// ---------------------------------------------------------------------------
// Kernel B: approx sim via bf16 MFMA, upper-triangle 128x128 tiles.
// acc = Ehi*Ehi^T + Ehi*Elo^T + Elo*Ehi^T (3 K-passes, fp32 accumulate).
// 256 thr = 4 waves, each wave a 64x64 quadrant = 4x4 MFMA tiles 16x16x32.
// ---------------------------------------------------------------------------
#define BK 64
#define SKP 72  // padded LDS row stride (shorts): 144 B -> 4-bank rotation

__global__ __launch_bounds__(256) void sim_mfma(
    const unsigned short* __restrict__ Ehi,
    const unsigned short* __restrict__ Elo, float* __restrict__ C) {
  const int bx = blockIdx.x, by = blockIdx.y;
  if (bx < by) return;  // upper triangle (incl. diagonal)

  __shared__ __align__(16) unsigned short Asl[128 * SKP];
  __shared__ __align__(16) unsigned short Bsl[128 * SKP];
  const int t = threadIdx.x;
  const int lane = t & 63, w = t >> 6;
  const int wr = w >> 1, wc = w & 1;
  const int quad = lane >> 4, l16 = lane & 15;
  const int i0 = by * 128, j0 = bx * 128;

  f32x4 acc[4][4];
#pragma unroll
  for (int a = 0; a < 4; ++a)
#pragma unroll
    for (int b = 0; b < 4; ++b) acc[a][b] = (f32x4){0.f, 0.f, 0.f, 0.f};

  const unsigned short* Ap[3] = {Ehi, Ehi, Elo};
  const unsigned short* Bp[3] = {Ehi, Elo, Ehi};

  const int sr = t >> 1;          // staging row 0..127 (2 threads/row)
  const int sc = (t & 1) * 32;    // staging k-offset (shorts): 0 or 32

  for (int p = 0; p < 3; ++p) {
    const unsigned short* Ag = Ap[p] + (size_t)i0 * DD;
    const unsigned short* Bg = Bp[p] + (size_t)j0 * DD;
    for (int kk = 0; kk < DD; kk += BK) {
      __syncthreads();  // protect LDS from previous iteration's readers
      // stage 128x64 shorts for A and B: each thread 4x16B per matrix
#pragma unroll
      for (int q = 0; q < 4; ++q) {
        int c = sc + q * 8;
        *(uint4*)&Asl[sr * SKP + c] = *(const uint4*)&Ag[(size_t)sr * DD + kk + c];
        *(uint4*)&Bsl[sr * SKP + c] = *(const uint4*)&Bg[(size_t)sr * DD + kk + c];
      }
      __syncthreads();
#pragma unroll
      for (int ks = 0; ks < 2; ++ks) {
        short8 af[4], bf[4];
#pragma unroll
        for (int mt = 0; mt < 4; ++mt)
          af[mt] = *(const short8*)&Asl[(wr * 64 + mt * 16 + l16) * SKP + ks * 32 + quad * 8];
#pragma unroll
        for (int nt = 0; nt < 4; ++nt)
          bf[nt] = *(const short8*)&Bsl[(wc * 64 + nt * 16 + l16) * SKP + ks * 32 + quad * 8];
#pragma unroll
        for (int mt = 0; mt < 4; ++mt)
#pragma unroll
          for (int nt = 0; nt < 4; ++nt)
            acc[mt][nt] = __builtin_amdgcn_mfma_f32_16x16x32_bf16(
                af[mt], bf[nt], acc[mt][nt], 0, 0, 0);
      }
    }
  }

  // C/D layout (verified m89/m91): col = lane&15, row = quad*4 + reg
#pragma unroll
  for (int mt = 0; mt < 4; ++mt)
#pragma unroll
    for (int r = 0; r < 4; ++r) {
      int row = i0 + wr * 64 + mt * 16 + quad * 4 + r;
      float* Cr = C + (size_t)row * NN + j0 + wc * 64;
#pragma unroll
      for (int nt = 0; nt < 4; ++nt) Cr[nt * 16 + l16] = acc[mt][nt][r];
    }
}

// ---------------------------------------------------------------------------
// Kernel C: mirror lower triangle: C[j][i] = C[i][j] via LDS transpose,
// coalesced reads and writes (32-row strips).
// ---------------------------------------------------------------------------
__global__ __launch_bounds__(256) void mirror_kernel(float* __restrict__ C) {
  const int bx = blockIdx.x, by = blockIdx.y;
  if (bx <= by) return;
  __shared__ float ts[32][132];
  const int t = threadIdx.x;
  const int i0 = by * 128, j0 = bx * 128;

  for (int s = 0; s < 4; ++s) {
    // read 32 src rows x 128 cols (1024 float4, 4/thread)
#pragma unroll
    for (int q = 0; q < 4; ++q) {
      int idx = q * 256 + t;
      int r = idx >> 5;            // 0..31
      int c4 = (idx & 31) * 4;     // 0..124
      float4 v = *(const float4*)&C[(size_t)(i0 + s * 32 + r) * NN + j0 + c4];
      ts[r][c4] = v.x; ts[r][c4 + 1] = v.y; ts[r][c4 + 2] = v.z; ts[r][c4 + 3] = v.w;
    }
    __syncthreads();
    // write 128 dst rows x 32 cols (transposed), coalesced float4
#pragma unroll
    for (int q = 0; q < 4; ++q) {
      int idx = q * 256 + t;
      int cc = idx >> 3;           // dst row (src col) 0..127
      int rr = (idx & 7) * 4;      // src row group 0..28
      float4 v = make_float4(ts[rr][cc], ts[rr + 1][cc], ts[rr + 2][cc], ts[rr + 3][cc]);
      *(float4*)&C[(size_t)(j0 + cc) * NN + i0 + s * 32 + rr] = v;
    }
    __syncthreads();
  }
}

// ---------------------------------------------------------------------------
// Kernel D: per-row top-31 on approx values with margin + exact re-ranking.
// ---------------------------------------------------------------------------
__global__ __launch_bounds__(256) void topk_kernel(float* __restrict__ C,
                                                   const float* __restrict__ e32) {
  const int row = blockIdx.x;
  const int tid = threadIdx.x;
  const int lane = tid & 63, wid = tid >> 6;

  __shared__ float sv[NN];     // 32 KB approx row
  __shared__ float er[DD];     // 2 KB e32 row i
  __shared__ unsigned long long wred[4];
  __shared__ int cand[CAP];
  __shared__ float cex[CAP];
  __shared__ int s_cnt;
  __shared__ int kidx[TOPK];
  __shared__ float kval[TOPK];

  float* Crow = C + (size_t)row * NN;
  float4* sv4 = (float4*)sv;
  const float4* Cr4 = (const float4*)Crow;
  for (int i = tid; i < NN / 4; i += 256) sv4[i] = Cr4[i];
  {
    const float4* e4 = (const float4*)(e32 + (size_t)row * DD);
    if (tid < DD / 4) ((float4*)er)[tid] = e4[tid];
  }
  if (tid == 0) s_cnt = 0;
  __syncthreads();

  // per-thread max over strided slice
  float myv = -FLT_MAX;
  for (int j = tid; j < NN; j += 256) {
    float v = sv[j];
    if (v > myv) myv = v;
  }

  // T = 31st-largest of the 256 thread maxima (<= true 31st row value)
  float T = 0.f;
  for (int it = 0; it < TOPK; ++it) {
    unsigned int u = __float_as_uint(myv);
    u = (u & 0x80000000u) ? ~u : (u | 0x80000000u);
    unsigned long long key = ((unsigned long long)u << 32) | (unsigned int)(255 - tid);
#pragma unroll
    for (int off = 32; off; off >>= 1) {
      unsigned long long o = __shfl_xor(key, off);
      if (o > key) key = o;
    }
    if (lane == 0) wred[wid] = key;
    __syncthreads();
    unsigned long long k0 = wred[0];
    if (wred[1] > k0) k0 = wred[1];
    if (wred[2] > k0) k0 = wred[2];
    if (wred[3] > k0) k0 = wred[3];
    if (it == TOPK - 1) {
      unsigned int uu = (unsigned int)(k0 >> 32);
      uu = (uu & 0x80000000u) ? (uu & 0x7fffffffu) : ~uu;
      T = __uint_as_float(uu);
    }
    if (tid == (int)(255u - (unsigned int)(k0 & 0xFFu))) myv = -FLT_MAX;
    __syncthreads();
  }

  // collect candidates with margin (covers exact top-31: |approx-exact|<=DELTA)
  const float Tc = T - 2.0f * DELTA;
  for (int j = tid; j < NN; j += 256) {
    if (sv[j] >= Tc) {
      int p = atomicAdd(&s_cnt, 1);
      if (p < CAP) cand[p] = j;
    }
  }
  __syncthreads();
  const int cnt = s_cnt;

  if (cnt <= CAP) {
    // exact sequential-k fmaf chains for candidates (bit-identical to ref chain)
    for (int c = tid; c < cnt; c += 256) {
      const float* ej = e32 + (size_t)cand[c] * DD;
      float a = 0.f;
      for (int k = 0; k < DD; k += 4) {
        float4 v = *(const float4*)&ej[k];
        a = fmaf(er[k], v.x, a);
        a = fmaf(er[k + 1], v.y, a);
        a = fmaf(er[k + 2], v.z, a);
        a = fmaf(er[k + 3], v.w, a);
      }
      cex[c] = a;
    }
    __syncthreads();
    // stable top-31 by (exact desc, idx asc); rank is unique
    for (int c = tid; c < cnt; c += 256) {
      float v = cex[c];
      int idx = cand[c];
      int rank = 0;
      for (int c2 = 0; c2 < cnt; ++c2) {
        float v2 = cex[c2];
        int idx2 = cand[c2];
        if (v2 > v || (v2 == v && idx2 < idx)) ++rank;
      }
      if (rank < TOPK) { kidx[rank] = idx; kval[rank] = v; }
    }
    __syncthreads();
  } else {
    // guaranteed-correct fallback (statistically unreachable):
    // recompute the EXACT chain for every column, then 31 argmax rounds.
    for (int m = 0; m < NN / 256; ++m) {
      int j = m * 256 + tid;
      const float* ej = e32 + (size_t)j * DD;
      float a = 0.f;
      for (int k = 0; k < DD; k += 4) {
        float4 v = *(const float4*)&ej[k];
        a = fmaf(er[k], v.x, a);
        a = fmaf(er[k + 1], v.y, a);
        a = fmaf(er[k + 2], v.z, a);
        a = fmaf(er[k + 3], v.w, a);
      }
      sv[j] = a;
    }
    __syncthreads();
    for (int it = 0; it < TOPK; ++it) {
      float bv = -FLT_MAX;
      int bi = 0;
      for (int j = tid; j < NN; j += 256) {
        float v = sv[j];
        if (v > bv) { bv = v; bi = j; }
      }
      unsigned int u = __float_as_uint(bv);
      u = (u & 0x80000000u) ? ~u : (u | 0x80000000u);
      unsigned long long key =
          ((unsigned long long)u << 32) | (unsigned int)(NN - 1 - bi);
#pragma unroll
      for (int off = 32; off; off >>= 1) {
        unsigned long long o = __shfl_xor(key, off);
        if (o > key) key = o;
      }
      if (lane == 0) wred[wid] = key;
      __syncthreads();
      if (tid == 0) {
        unsigned long long k0 = wred[0];
        if (wred[1] > k0) k0 = wred[1];
        if (wred[2] > k0) k0 = wred[2];
        if (wred[3] > k0) k0 = wred[3];
        int idx = (NN - 1) - (int)(k0 & 0xFFFFFFFFu);
        kidx[it] = idx;
        kval[it] = sv[idx];
        sv[idx] = -FLT_MAX;
      }
      __syncthreads();
    }
  }

  // write: zeros + relu(exact kept values)
  float4 z4 = make_float4(0.f, 0.f, 0.f, 0.f);
  for (int i = tid; i < NN / 4; i += 256) sv4[i] = z4;
  __syncthreads();
  if (tid < TOPK) sv[kidx[tid]] = fmaxf(kval[tid], 0.0f);
  __syncthreads();
  float4* Cw4 = (float4*)Crow;
  for (int i = tid; i < NN / 4; i += 256) Cw4[i] = sv4[i];
}

// ---------------------------------------------------------------------------
extern "C" void kernel_launch(void* const* d_in, const int* in_sizes, int n_in,
                              void* d_out, int out_size, void* d_ws,
                              size_t ws_size, hipStream_t stream) {
  const float* f = (const float*)d_in[0];
  const float* W1 = (const float*)d_in[1];
  const float* W2 = (const float*)d_in[2];
  float* out = (float*)d_out;
  float* e32 = (float*)d_ws;                                  // 16 MiB
  unsigned short* Ehi = (unsigned short*)((char*)d_ws + (size_t)NN * DD * 4);  // 8 MiB
  unsigned short* Elo = Ehi + (size_t)NN * DD;                                 // 8 MiB

  emb_kernel<<<NN / 4, 256, 0, stream>>>(f, W1, W2, e32, Ehi, Elo);
  dim3 g2(NN / 128, NN / 128);
  sim_mfma<<<g2, 256, 0, stream>>>(Ehi, Elo, out);
  mirror_kernel<<<g2, 256, 0, stream>>>(out);
  topk_kernel<<<NN, 256, 0, stream>>>(out, e32);
}

// Round 6
// 785.415 us; speedup vs baseline: 2.0179x; 1.1891x over previous
//
#include <hip/hip_runtime.h>
#include <float.h>
#include <math.h>

// Problem constants (fixed by the reference: N=8192, D=512, k+1=31).
#define NN 8192
#define DD 512
#define TOPK 31
#define CAPW 512          // per-wave candidate cap (typical cnt ~40)
#define DELTA 1e-4f       // >= 5x the guaranteed |approx-exact| bound (~2e-5)

// Strategy (R5/R6):
//   Values chain (bit-exact vs np ref, absmax 0.0 since R3):
//     h = relu(f*W1)*W2 ; n = sqrtf(numpy-pairwise sum h*h) ; e = h/n
//     sim[i][j] = sequential-k fmaf chain over e_i*e_j
//   sim computed approximately with bf16 MFMA (e = hi+lo split, 3 passes),
//   upper-triangle + mirror. topk (R6: one WAVE per row, zero block barriers)
//   collects candidates with margin, recomputes exact chains, selects by
//   (exact desc, idx asc). Overflow rows -> flag -> exact cleanup kernel.

typedef __attribute__((ext_vector_type(8))) short short8;
typedef __attribute__((ext_vector_type(4))) float f32x4;

__device__ __forceinline__ float h_elem(const float* __restrict__ f,
                                        const float* __restrict__ W1,
                                        const float* __restrict__ W2, int k) {
  float x = f[k] * W1[k];
  x = fmaxf(x, 0.0f);
  return x * W2[k];
}

__device__ __forceinline__ unsigned short f2bf_rne(float x) {
  unsigned u = __float_as_uint(x);
  unsigned r = (u >> 16) & 1u;
  u += 0x7fffu + r;
  return (unsigned short)(u >> 16);
}
__device__ __forceinline__ float bf2f(unsigned short h) {
  return __uint_as_float(((unsigned)h) << 16);
}
__device__ __forceinline__ unsigned ordmap(float x) {
  unsigned u = __float_as_uint(x);
  return (u & 0x80000000u) ? ~u : (u | 0x80000000u);
}
__device__ __forceinline__ float ordunmap(unsigned u) {
  return __uint_as_float((u & 0x80000000u) ? (u & 0x7fffffffu) : ~u);
}

// ---------------------------------------------------------------------------
// Kernel A: fused norm (numpy pairwise association, bit-exact) + e = h/n,
// bf16 hi/lo split, and per-row overflow-flag zeroing. One wave per row.
// ---------------------------------------------------------------------------
__global__ __launch_bounds__(256) void emb_kernel(
    const float* __restrict__ f, const float* __restrict__ W1,
    const float* __restrict__ W2, float* __restrict__ e32,
    unsigned short* __restrict__ Ehi, unsigned short* __restrict__ Elo,
    int* __restrict__ flags) {
  const int lane = threadIdx.x & 63;
  const int row = blockIdx.x * 4 + (threadIdx.x >> 6);
  const float* fr = f + (size_t)row * DD;
  const int b = lane >> 4, L = lane & 15;
  if (lane == 0) flags[row] = 0;

  float s[8];
#pragma unroll
  for (int j = 0; j < 8; ++j) {
    float h = h_elem(fr, W1, W2, b * 128 + 16 * j + L);
    s[j] = h * h;
  }
  float v = ((s[0] + s[1]) + (s[2] + s[3])) + ((s[4] + s[5]) + (s[6] + s[7]));
  float t = v + __shfl_xor(v, 8);
  t = t + __shfl_xor(t, 4);
  t = t + __shfl_xor(t, 2);
  float nb = t + __shfl_xor(t, 1);
  float x = nb + __shfl_xor(nb, 16);
  float norm2 = x + __shfl_xor(x, 32);
  const float n = fmaxf(sqrtf(norm2), 1e-12f);

  float* er = e32 + (size_t)row * DD;
  unsigned short* hr = Ehi + (size_t)row * DD;
  unsigned short* lr = Elo + (size_t)row * DD;
#pragma unroll
  for (int m = 0; m < 8; ++m) {
    int k = m * 64 + lane;
    float e = h_elem(fr, W1, W2, k) / n;
    er[k] = e;
    unsigned short hb = f2bf_rne(e);
    hr[k] = hb;
    lr[k] = f2bf_rne(e - bf2f(hb));
  }
}

// ---------------------------------------------------------------------------
// Kernel B: approx sim via bf16 MFMA, upper-triangle 128x128 tiles.
// acc = Ehi*Ehi^T + Ehi*Elo^T + Elo*Ehi^T (3 K-passes, fp32 accumulate).
// ---------------------------------------------------------------------------
#define BK 64
#define SKP 72

__global__ __launch_bounds__(256) void sim_mfma(
    const unsigned short* __restrict__ Ehi,
    const unsigned short* __restrict__ Elo, float* __restrict__ C) {
  const int bx = blockIdx.x, by = blockIdx.y;
  if (bx < by) return;

  __shared__ __align__(16) unsigned short Asl[128 * SKP];
  __shared__ __align__(16) unsigned short Bsl[128 * SKP];
  const int t = threadIdx.x;
  const int lane = t & 63, w = t >> 6;
  const int wr = w >> 1, wc = w & 1;
  const int quad = lane >> 4, l16 = lane & 15;
  const int i0 = by * 128, j0 = bx * 128;

  f32x4 acc[4][4];
#pragma unroll
  for (int a = 0; a < 4; ++a)
#pragma unroll
    for (int b = 0; b < 4; ++b) acc[a][b] = (f32x4){0.f, 0.f, 0.f, 0.f};

  const unsigned short* Ap[3] = {Ehi, Ehi, Elo};
  const unsigned short* Bp[3] = {Ehi, Elo, Ehi};

  const int sr = t >> 1;
  const int sc = (t & 1) * 32;

  for (int p = 0; p < 3; ++p) {
    const unsigned short* Ag = Ap[p] + (size_t)i0 * DD;
    const unsigned short* Bg = Bp[p] + (size_t)j0 * DD;
    for (int kk = 0; kk < DD; kk += BK) {
      __syncthreads();
#pragma unroll
      for (int q = 0; q < 4; ++q) {
        int c = sc + q * 8;
        *(uint4*)&Asl[sr * SKP + c] = *(const uint4*)&Ag[(size_t)sr * DD + kk + c];
        *(uint4*)&Bsl[sr * SKP + c] = *(const uint4*)&Bg[(size_t)sr * DD + kk + c];
      }
      __syncthreads();
#pragma unroll
      for (int ks = 0; ks < 2; ++ks) {
        short8 af[4], bf[4];
#pragma unroll
        for (int mt = 0; mt < 4; ++mt)
          af[mt] = *(const short8*)&Asl[(wr * 64 + mt * 16 + l16) * SKP + ks * 32 + quad * 8];
#pragma unroll
        for (int nt = 0; nt < 4; ++nt)
          bf[nt] = *(const short8*)&Bsl[(wc * 64 + nt * 16 + l16) * SKP + ks * 32 + quad * 8];
#pragma unroll
        for (int mt = 0; mt < 4; ++mt)
#pragma unroll
          for (int nt = 0; nt < 4; ++nt)
            acc[mt][nt] = __builtin_amdgcn_mfma_f32_16x16x32_bf16(
                af[mt], bf[nt], acc[mt][nt], 0, 0, 0);
      }
    }
  }

#pragma unroll
  for (int mt = 0; mt < 4; ++mt)
#pragma unroll
    for (int r = 0; r < 4; ++r) {
      int row = i0 + wr * 64 + mt * 16 + quad * 4 + r;
      float* Cr = C + (size_t)row * NN + j0 + wc * 64;
#pragma unroll
      for (int nt = 0; nt < 4; ++nt) Cr[nt * 16 + l16] = acc[mt][nt][r];
    }
}

// ---------------------------------------------------------------------------
// Kernel C: mirror lower triangle via LDS transpose (coalesced both sides).
// ---------------------------------------------------------------------------
__global__ __launch_bounds__(256) void mirror_kernel(float* __restrict__ C) {
  const int bx = blockIdx.x, by = blockIdx.y;
  if (bx <= by) return;
  __shared__ float ts[32][132];
  const int t = threadIdx.x;
  const int i0 = by * 128, j0 = bx * 128;

  for (int s = 0; s < 4; ++s) {
#pragma unroll
    for (int q = 0; q < 4; ++q) {
      int idx = q * 256 + t;
      int r = idx >> 5;
      int c4 = (idx & 31) * 4;
      float4 v = *(const float4*)&C[(size_t)(i0 + s * 32 + r) * NN + j0 + c4];
      ts[r][c4] = v.x; ts[r][c4 + 1] = v.y; ts[r][c4 + 2] = v.z; ts[r][c4 + 3] = v.w;
    }
    __syncthreads();
#pragma unroll
    for (int q = 0; q < 4; ++q) {
      int idx = q * 256 + t;
      int cc = idx >> 3;
      int rr = (idx & 7) * 4;
      float4 v = make_float4(ts[rr][cc], ts[rr + 1][cc], ts[rr + 2][cc], ts[rr + 3][cc]);
      *(float4*)&C[(size_t)(j0 + cc) * NN + i0 + s * 32 + rr] = v;
    }
    __syncthreads();
  }
}

// ---------------------------------------------------------------------------
// Kernel D (R6): one WAVE per row, no block barriers.
//  P1 stream row -> lane max          P2 T = 31st of 64 lane maxima (shuffles)
//  P3 re-stream, collect v >= T-2d    P4 exact chains for candidates
//  P5 rank -> top-31 + bitmap         P6 stream-write 0-or-value
// Overflow (cnt > CAPW): flag row for exact cleanup kernel.
// ---------------------------------------------------------------------------
__global__ __launch_bounds__(256) void topk_kernel(float* __restrict__ C,
                                                   const float* __restrict__ e32,
                                                   int* __restrict__ flags) {
  const int w = threadIdx.x >> 6;
  const int lane = threadIdx.x & 63;
  const int row = blockIdx.x * 4 + w;

  __shared__ float er[4][DD];                      // 8 KB
  __shared__ int cidx[4][CAPW];                    // 8 KB
  __shared__ float cval[4][CAPW];                  // 8 KB
  __shared__ unsigned long long bmap[4][NN / 64];  // 4 KB
  __shared__ int wcnt[4];
  __shared__ int kidx[4][TOPK];
  __shared__ float kval[4][TOPK];

  // load e32 row into LDS (wave-local)
  {
    const float4* e4 = (const float4*)(e32 + (size_t)row * DD);
    float4* er4 = (float4*)er[w];
#pragma unroll
    for (int q = 0; q < 2; ++q) er4[q * 64 + lane] = e4[q * 64 + lane];
  }

  float* Crow = C + (size_t)row * NN;
  const float4* Cr4 = (const float4*)Crow;

  // P1: stream + lane max
  float mymax = -FLT_MAX;
#pragma unroll 4
  for (int it = 0; it < 32; ++it) {
    float4 v = Cr4[it * 64 + lane];
    mymax = fmaxf(mymax, fmaxf(fmaxf(v.x, v.y), fmaxf(v.z, v.w)));
  }

  // P2: T = 31st largest of the 64 lane maxima (all-shuffle, unique winners)
  float mv = mymax, T = 0.f;
  for (int it = 0; it < TOPK; ++it) {
    unsigned long long key =
        ((unsigned long long)ordmap(mv) << 32) | (unsigned)(63 - lane);
#pragma unroll
    for (int off = 32; off; off >>= 1) {
      unsigned long long o = __shfl_xor(key, off);
      if (o > key) key = o;
    }
    if (it == TOPK - 1) T = ordunmap((unsigned)(key >> 32));
    if (lane == 63 - (int)(key & 63u)) mv = -FLT_MAX;
  }

  // init wave-local counters/bitmap (wave-synchronous, no barrier needed)
  if (lane == 0) wcnt[w] = 0;
#pragma unroll
  for (int q = 0; q < 2; ++q) bmap[w][q * 64 + lane] = 0ull;

  // P3: collect candidates with margin
  const float Tc = T - 2.0f * DELTA;
  for (int it = 0; it < 32; ++it) {
    float4 v = Cr4[it * 64 + lane];
    int j = (it * 64 + lane) * 4;
    if (v.x >= Tc) { int p = atomicAdd(&wcnt[w], 1); if (p < CAPW) cidx[w][p] = j; }
    if (v.y >= Tc) { int p = atomicAdd(&wcnt[w], 1); if (p < CAPW) cidx[w][p] = j + 1; }
    if (v.z >= Tc) { int p = atomicAdd(&wcnt[w], 1); if (p < CAPW) cidx[w][p] = j + 2; }
    if (v.w >= Tc) { int p = atomicAdd(&wcnt[w], 1); if (p < CAPW) cidx[w][p] = j + 3; }
  }
  const int cnt = wcnt[w];

  if (cnt > CAPW) {  // statistically unreachable; exact cleanup handles it
    if (lane == 0) flags[row] = 1;
    return;
  }

  // P4: exact sequential-k fmaf chains (bit-identical to the verified chain)
  for (int c = lane; c < cnt; c += 64) {
    const float4* ej4 = (const float4*)(e32 + (size_t)cidx[w][c] * DD);
    float a = 0.f;
    for (int k4 = 0; k4 < DD / 4; ++k4) {
      float4 vv = ej4[k4];
      const float* e = &er[w][k4 * 4];
      a = fmaf(e[0], vv.x, a);
      a = fmaf(e[1], vv.y, a);
      a = fmaf(e[2], vv.z, a);
      a = fmaf(e[3], vv.w, a);
    }
    cval[w][c] = a;
  }

  // P5: stable top-31 by (exact desc, idx asc); set bitmap
  for (int c = lane; c < cnt; c += 64) {
    float v = cval[w][c];
    int idx = cidx[w][c];
    int rank = 0;
    for (int c2 = 0; c2 < cnt; ++c2) {
      float v2 = cval[w][c2];
      if (v2 > v || (v2 == v && cidx[w][c2] < idx)) ++rank;
    }
    if (rank < TOPK) {
      kidx[w][rank] = idx;
      kval[w][rank] = fmaxf(v, 0.0f);  // relu
      atomicOr(&bmap[w][idx >> 6], 1ull << (idx & 63));
    }
  }

  // P6: stream-write the output row (0 or kept value)
  float4* Cw4 = (float4*)Crow;
  for (int it = 0; it < 32; ++it) {
    int j4 = (it * 64 + lane) * 4;
    float4 o = make_float4(0.f, 0.f, 0.f, 0.f);
    unsigned long long word = bmap[w][j4 >> 6];
    unsigned nib = (unsigned)((word >> (j4 & 63)) & 0xFull);
    if (nib) {
#pragma unroll
      for (int c = 0; c < 4; ++c)
        if ((nib >> c) & 1u) {
          int j = j4 + c;
          float val = 0.f;
          for (int s = 0; s < TOPK; ++s)
            if (kidx[w][s] == j) val = kval[w][s];
          ((float*)&o)[c] = val;
        }
    }
    Cw4[it * 64 + lane] = o;
  }
}

// ---------------------------------------------------------------------------
// Kernel E: exact cleanup for flagged rows (statistically never executes).
// Full exact chains for all 8192 cols + 31 argmax rounds, then write.
// ---------------------------------------------------------------------------
__global__ __launch_bounds__(256) void cleanup_kernel(
    float* __restrict__ C, const float* __restrict__ e32,
    const int* __restrict__ flags) {
  const int row = blockIdx.x;
  if (flags[row] == 0) return;
  const int tid = threadIdx.x;
  const int lane = tid & 63, wid = tid >> 6;

  __shared__ float sv[NN];
  __shared__ float er[DD];
  __shared__ unsigned long long wred[4];
  __shared__ int kidx[TOPK];
  __shared__ float kval[TOPK];

  {
    const float4* e4 = (const float4*)(e32 + (size_t)row * DD);
    if (tid < DD / 4) ((float4*)er)[tid] = e4[tid];
  }
  __syncthreads();

  for (int m = 0; m < NN / 256; ++m) {
    int j = m * 256 + tid;
    const float* ej = e32 + (size_t)j * DD;
    float a = 0.f;
    for (int k = 0; k < DD; k += 4) {
      float4 v = *(const float4*)&ej[k];
      a = fmaf(er[k], v.x, a);
      a = fmaf(er[k + 1], v.y, a);
      a = fmaf(er[k + 2], v.z, a);
      a = fmaf(er[k + 3], v.w, a);
    }
    sv[j] = a;
  }
  __syncthreads();

  for (int it = 0; it < TOPK; ++it) {
    float bv = -FLT_MAX;
    int bi = 0;
    for (int j = tid; j < NN; j += 256) {
      float v = sv[j];
      if (v > bv) { bv = v; bi = j; }
    }
    unsigned long long key =
        ((unsigned long long)ordmap(bv) << 32) | (unsigned)(NN - 1 - bi);
#pragma unroll
    for (int off = 32; off; off >>= 1) {
      unsigned long long o = __shfl_xor(key, off);
      if (o > key) key = o;
    }
    if (lane == 0) wred[wid] = key;
    __syncthreads();
    if (tid == 0) {
      unsigned long long k0 = wred[0];
      if (wred[1] > k0) k0 = wred[1];
      if (wred[2] > k0) k0 = wred[2];
      if (wred[3] > k0) k0 = wred[3];
      int idx = (NN - 1) - (int)(k0 & 0xFFFFFFFFu);
      kidx[it] = idx;
      kval[it] = sv[idx];
      sv[idx] = -FLT_MAX;
    }
    __syncthreads();
  }

  float4 z4 = make_float4(0.f, 0.f, 0.f, 0.f);
  float4* sv4 = (float4*)sv;
  for (int i = tid; i < NN / 4; i += 256) sv4[i] = z4;
  __syncthreads();
  if (tid < TOPK) sv[kidx[tid]] = fmaxf(kval[tid], 0.0f);
  __syncthreads();
  float4* Cw4 = (float4*)(C + (size_t)row * NN);
  for (int i = tid; i < NN / 4; i += 256) Cw4[i] = sv4[i];
}

// ---------------------------------------------------------------------------
extern "C" void kernel_launch(void* const* d_in, const int* in_sizes, int n_in,
                              void* d_out, int out_size, void* d_ws,
                              size_t ws_size, hipStream_t stream) {
  const float* f = (const float*)d_in[0];
  const float* W1 = (const float*)d_in[1];
  const float* W2 = (const float*)d_in[2];
  float* out = (float*)d_out;
  float* e32 = (float*)d_ws;                                                   // 16 MiB
  unsigned short* Ehi = (unsigned short*)((char*)d_ws + (size_t)NN * DD * 4);  // 8 MiB
  unsigned short* Elo = Ehi + (size_t)NN * DD;                                 // 8 MiB
  int* flags = (int*)((char*)d_ws + (size_t)NN * DD * 8);                      // 32 KB

  emb_kernel<<<NN / 4, 256, 0, stream>>>(f, W1, W2, e32, Ehi, Elo, flags);
  dim3 g2(NN / 128, NN / 128);
  sim_mfma<<<g2, 256, 0, stream>>>(Ehi, Elo, out);
  mirror_kernel<<<g2, 256, 0, stream>>>(out);
  topk_kernel<<<NN / 4, 256, 0, stream>>>(out, e32, flags);
  cleanup_kernel<<<NN, 256, 0, stream>>>(out, e32, flags);
}

// Round 7
// 671.610 us; speedup vs baseline: 2.3598x; 1.1695x over previous
//
#include <hip/hip_runtime.h>
#include <float.h>
#include <math.h>

// Problem constants (fixed by the reference: N=8192, D=512, k+1=31).
#define NN 8192
#define DD 512
#define TOPK 31
#define CAPW 512          // per-wave candidate cap (typical cnt ~50)
#define DELTA 1e-4f       // sound |approx-exact| bound: lo*lo + requant ~5e-5

// Strategy (R7):
//   Bit-exact value chain (absmax 0.0 since R3):
//     h = relu(f*W1)*W2 ; n = sqrtf(numpy-pairwise sum h*h) ; e = h/n
//     sim[i][j] = sequential-k fmaf chain over e_i*e_j ; stable top-31
//   Approx sim = bf16 MFMA: e = hi+lo, acc = hi*hi + lo*hi + hi*lo (one
//   merged K-loop, 4 tiles staged per k-block). Upper-triangle blocks only;
//   epilogue writes the normal tile, the transposed (mirror) tile via LDS,
//   and per-row tile-maxima TM. topk: T = 31st tile-max, one row pass
//   collects candidates >= T-2*DELTA, exact chains re-rank, write.

typedef __attribute__((ext_vector_type(8))) short short8;
typedef __attribute__((ext_vector_type(4))) float f32x4;

__device__ __forceinline__ float h_elem(const float* __restrict__ f,
                                        const float* __restrict__ W1,
                                        const float* __restrict__ W2, int k) {
  float x = f[k] * W1[k];
  x = fmaxf(x, 0.0f);
  return x * W2[k];
}

__device__ __forceinline__ unsigned short f2bf_rne(float x) {
  unsigned u = __float_as_uint(x);
  unsigned r = (u >> 16) & 1u;
  u += 0x7fffu + r;
  return (unsigned short)(u >> 16);
}
__device__ __forceinline__ float bf2f(unsigned short h) {
  return __uint_as_float(((unsigned)h) << 16);
}
__device__ __forceinline__ unsigned ordmap(float x) {
  unsigned u = __float_as_uint(x);
  return (u & 0x80000000u) ? ~u : (u | 0x80000000u);
}
__device__ __forceinline__ float ordunmap(unsigned u) {
  return __uint_as_float((u & 0x80000000u) ? (u & 0x7fffffffu) : ~u);
}

// ---------------------------------------------------------------------------
// Kernel A: fused norm (numpy pairwise association, bit-exact) + e = h/n,
// bf16 hi/lo split, flag zeroing. One wave per row.
// ---------------------------------------------------------------------------
__global__ __launch_bounds__(256) void emb_kernel(
    const float* __restrict__ f, const float* __restrict__ W1,
    const float* __restrict__ W2, float* __restrict__ e32,
    unsigned short* __restrict__ Ehi, unsigned short* __restrict__ Elo,
    int* __restrict__ flags) {
  const int lane = threadIdx.x & 63;
  const int row = blockIdx.x * 4 + (threadIdx.x >> 6);
  const float* fr = f + (size_t)row * DD;
  const int b = lane >> 4, L = lane & 15;
  if (lane == 0) flags[row] = 0;

  float s[8];
#pragma unroll
  for (int j = 0; j < 8; ++j) {
    float h = h_elem(fr, W1, W2, b * 128 + 16 * j + L);
    s[j] = h * h;
  }
  float v = ((s[0] + s[1]) + (s[2] + s[3])) + ((s[4] + s[5]) + (s[6] + s[7]));
  float t = v + __shfl_xor(v, 8);
  t = t + __shfl_xor(t, 4);
  t = t + __shfl_xor(t, 2);
  float nb = t + __shfl_xor(t, 1);
  float x = nb + __shfl_xor(nb, 16);
  float norm2 = x + __shfl_xor(x, 32);
  const float n = fmaxf(sqrtf(norm2), 1e-12f);

  float* er = e32 + (size_t)row * DD;
  unsigned short* hr = Ehi + (size_t)row * DD;
  unsigned short* lr = Elo + (size_t)row * DD;
#pragma unroll
  for (int m = 0; m < 8; ++m) {
    int k = m * 64 + lane;
    float e = h_elem(fr, W1, W2, k) / n;
    er[k] = e;
    unsigned short hb = f2bf_rne(e);
    hr[k] = hb;
    lr[k] = f2bf_rne(e - bf2f(hb));
  }
}

// ---------------------------------------------------------------------------
// Kernel B: merged 3-term bf16 MFMA sim, upper-triangle 128x128 tiles.
// One K-loop (BK=32) staging Ahi/Alo/Bhi/Blo; 48 MFMAs per barrier pair.
// Epilogue: normal tile write + per-row tile-max TM + (bx>by) transposed
// mirror tile via LDS strips + transposed TM.
// LDS tiles: stride 40 shorts -> frag read banks (20r+4q)%32, 2-way max.
// ---------------------------------------------------------------------------
#define TSTR 40                     // LDS tile row stride in shorts
#define OF_AH 0
#define OF_AL (128 * TSTR)
#define OF_BH (2 * 128 * TSTR)
#define OF_BL (3 * 128 * TSTR)

__global__ __launch_bounds__(256) void sim_mfma(
    const unsigned short* __restrict__ Ehi,
    const unsigned short* __restrict__ Elo, float* __restrict__ C,
    float* __restrict__ TM) {
  const int bx = blockIdx.x, by = blockIdx.y;
  if (bx < by) return;

  __shared__ __align__(16) char smem[4 * 128 * TSTR * 2];  // 40960 B
  unsigned short* S = (unsigned short*)smem;
  float(*Tt)[132] = (float(*)[132])smem;  // epilogue alias (33792 B)
  __shared__ float rmx[128][2];
  __shared__ float cmx[128][2];

  const int t = threadIdx.x;
  const int lane = t & 63, w = t >> 6;
  const int wr = w >> 1, wc = w & 1;
  const int quad = lane >> 4, l16 = lane & 15;
  const int i0 = by * 128, j0 = bx * 128;

  f32x4 acc[4][4];
#pragma unroll
  for (int a = 0; a < 4; ++a)
#pragma unroll
    for (int b = 0; b < 4; ++b) acc[a][b] = (f32x4){0.f, 0.f, 0.f, 0.f};

  const int sr = t >> 1;          // staging row 0..127
  const int c0 = (t & 1) * 16;    // staging k-offset in shorts: 0 or 16
  const size_t ga = (size_t)(i0 + sr) * DD;
  const size_t gb = (size_t)(j0 + sr) * DD;

  for (int kk = 0; kk < DD; kk += 32) {
    __syncthreads();
    uint4 ah0 = *(const uint4*)&Ehi[ga + kk + c0];
    uint4 ah1 = *(const uint4*)&Ehi[ga + kk + c0 + 8];
    uint4 al0 = *(const uint4*)&Elo[ga + kk + c0];
    uint4 al1 = *(const uint4*)&Elo[ga + kk + c0 + 8];
    uint4 bh0 = *(const uint4*)&Ehi[gb + kk + c0];
    uint4 bh1 = *(const uint4*)&Ehi[gb + kk + c0 + 8];
    uint4 bl0 = *(const uint4*)&Elo[gb + kk + c0];
    uint4 bl1 = *(const uint4*)&Elo[gb + kk + c0 + 8];
    *(uint4*)&S[OF_AH + sr * TSTR + c0] = ah0;
    *(uint4*)&S[OF_AH + sr * TSTR + c0 + 8] = ah1;
    *(uint4*)&S[OF_AL + sr * TSTR + c0] = al0;
    *(uint4*)&S[OF_AL + sr * TSTR + c0 + 8] = al1;
    *(uint4*)&S[OF_BH + sr * TSTR + c0] = bh0;
    *(uint4*)&S[OF_BH + sr * TSTR + c0 + 8] = bh1;
    *(uint4*)&S[OF_BL + sr * TSTR + c0] = bl0;
    *(uint4*)&S[OF_BL + sr * TSTR + c0 + 8] = bl1;
    __syncthreads();

    short8 ah[4], al[4], bh[4];
#pragma unroll
    for (int mt = 0; mt < 4; ++mt) {
      int rr = (wr * 64 + mt * 16 + l16) * TSTR + quad * 8;
      ah[mt] = *(const short8*)&S[OF_AH + rr];
      al[mt] = *(const short8*)&S[OF_AL + rr];
    }
#pragma unroll
    for (int nt = 0; nt < 4; ++nt)
      bh[nt] = *(const short8*)&S[OF_BH + (wc * 64 + nt * 16 + l16) * TSTR + quad * 8];
#pragma unroll
    for (int mt = 0; mt < 4; ++mt)
#pragma unroll
      for (int nt = 0; nt < 4; ++nt)
        acc[mt][nt] = __builtin_amdgcn_mfma_f32_16x16x32_bf16(ah[mt], bh[nt], acc[mt][nt], 0, 0, 0);
#pragma unroll
    for (int mt = 0; mt < 4; ++mt)
#pragma unroll
      for (int nt = 0; nt < 4; ++nt)
        acc[mt][nt] = __builtin_amdgcn_mfma_f32_16x16x32_bf16(al[mt], bh[nt], acc[mt][nt], 0, 0, 0);
    short8 bl[4];
#pragma unroll
    for (int nt = 0; nt < 4; ++nt)
      bl[nt] = *(const short8*)&S[OF_BL + (wc * 64 + nt * 16 + l16) * TSTR + quad * 8];
#pragma unroll
    for (int mt = 0; mt < 4; ++mt)
#pragma unroll
      for (int nt = 0; nt < 4; ++nt)
        acc[mt][nt] = __builtin_amdgcn_mfma_f32_16x16x32_bf16(ah[mt], bl[nt], acc[mt][nt], 0, 0, 0);
  }

  // --- normal tile write (C/D layout: col = lane&15, row = quad*4 + reg) ---
#pragma unroll
  for (int mt = 0; mt < 4; ++mt)
#pragma unroll
    for (int r = 0; r < 4; ++r) {
      int row = i0 + wr * 64 + mt * 16 + quad * 4 + r;
      float* Cr = C + (size_t)row * NN + j0 + wc * 64;
#pragma unroll
      for (int nt = 0; nt < 4; ++nt) Cr[nt * 16 + l16] = acc[mt][nt][r];
    }

  // --- per-row tile-max (rows of this tile) ---
#pragma unroll
  for (int mt = 0; mt < 4; ++mt)
#pragma unroll
    for (int r = 0; r < 4; ++r) {
      float m = fmaxf(fmaxf(acc[mt][0][r], acc[mt][1][r]),
                      fmaxf(acc[mt][2][r], acc[mt][3][r]));
      m = fmaxf(m, __shfl_xor(m, 1));
      m = fmaxf(m, __shfl_xor(m, 2));
      m = fmaxf(m, __shfl_xor(m, 4));
      m = fmaxf(m, __shfl_xor(m, 8));
      if (l16 == 0) rmx[wr * 64 + mt * 16 + quad * 4 + r][wc] = m;
    }
  // --- per-col tile-max (rows of the mirrored tile), only if off-diagonal ---
  if (bx > by) {
#pragma unroll
    for (int nt = 0; nt < 4; ++nt) {
      float c = -FLT_MAX;
#pragma unroll
      for (int mt = 0; mt < 4; ++mt)
#pragma unroll
        for (int r = 0; r < 4; ++r) c = fmaxf(c, acc[mt][nt][r]);
      c = fmaxf(c, __shfl_xor(c, 16));
      c = fmaxf(c, __shfl_xor(c, 32));
      if (quad == 0) cmx[wc * 64 + nt * 16 + l16][wr] = c;
    }
  }
  __syncthreads();
  if (t < 128) TM[(size_t)(i0 + t) * 64 + bx] = fmaxf(rmx[t][0], rmx[t][1]);
  if (bx > by) {
    if (t < 128) TM[(size_t)(j0 + t) * 64 + by] = fmaxf(cmx[t][0], cmx[t][1]);
    // --- transposed mirror write via LDS strips (Tt aliases S) ---
    for (int s = 0; s < 2; ++s) {
      __syncthreads();
      if (wc == s) {
#pragma unroll
        for (int mt = 0; mt < 4; ++mt)
#pragma unroll
          for (int nt = 0; nt < 4; ++nt)
#pragma unroll
            for (int r = 0; r < 4; ++r)
              Tt[nt * 16 + l16][wr * 64 + mt * 16 + quad * 4 + r] = acc[mt][nt][r];
      }
      __syncthreads();
#pragma unroll
      for (int q = 0; q < 8; ++q) {
        int fi = q * 256 + t;
        int rr = fi >> 5;
        int cc4 = (fi & 31) * 4;
        float4 v = make_float4(Tt[rr][cc4], Tt[rr][cc4 + 1], Tt[rr][cc4 + 2],
                               Tt[rr][cc4 + 3]);
        *(float4*)&C[(size_t)(j0 + s * 64 + rr) * NN + i0 + cc4] = v;
      }
    }
  }
}

// ---------------------------------------------------------------------------
// Kernel C: one WAVE per row. T = 31st largest tile-max (sound lower bound
// on 31st approx row value); single row pass collects cands >= T - 2*DELTA;
// exact fmaf chains re-rank; write zeros + relu(exact). Overflow -> flag.
// ---------------------------------------------------------------------------
__global__ __launch_bounds__(256) void topk_kernel(float* __restrict__ C,
                                                   const float* __restrict__ e32,
                                                   const float* __restrict__ TM,
                                                   int* __restrict__ flags) {
  const int w = threadIdx.x >> 6;
  const int lane = threadIdx.x & 63;
  const int row = blockIdx.x * 4 + w;

  __shared__ float er[4][DD];
  __shared__ int cidx[4][CAPW];
  __shared__ float cval[4][CAPW];
  __shared__ unsigned long long bmap[4][NN / 64];
  __shared__ int wcnt[4];
  __shared__ int kidx[4][TOPK];
  __shared__ float kval[4][TOPK];

  {
    const float4* e4 = (const float4*)(e32 + (size_t)row * DD);
    float4* er4 = (float4*)er[w];
    er4[lane] = e4[lane];
    er4[64 + lane] = e4[64 + lane];
  }

  // T = 31st largest of 64 tile maxima (shuffle argmax rounds)
  float mv = TM[(size_t)row * 64 + lane];
  float T = 0.f;
  for (int it = 0; it < TOPK; ++it) {
    unsigned long long key =
        ((unsigned long long)ordmap(mv) << 32) | (unsigned)(63 - lane);
#pragma unroll
    for (int off = 32; off; off >>= 1) {
      unsigned long long o = __shfl_xor(key, off);
      if (o > key) key = o;
    }
    if (it == TOPK - 1) T = ordunmap((unsigned)(key >> 32));
    if (lane == 63 - (int)(key & 63u)) mv = -FLT_MAX;
  }

  if (lane == 0) wcnt[w] = 0;
#pragma unroll
  for (int q = 0; q < 2; ++q) bmap[w][q * 64 + lane] = 0ull;

  // single row pass: collect candidates
  const float Tc = T - 2.0f * DELTA;
  float* Crow = C + (size_t)row * NN;
  const float4* Cr4 = (const float4*)Crow;
  for (int it = 0; it < 32; ++it) {
    float4 v = Cr4[it * 64 + lane];
    int j = (it * 64 + lane) * 4;
    if (v.x >= Tc) { int p = atomicAdd(&wcnt[w], 1); if (p < CAPW) cidx[w][p] = j; }
    if (v.y >= Tc) { int p = atomicAdd(&wcnt[w], 1); if (p < CAPW) cidx[w][p] = j + 1; }
    if (v.z >= Tc) { int p = atomicAdd(&wcnt[w], 1); if (p < CAPW) cidx[w][p] = j + 2; }
    if (v.w >= Tc) { int p = atomicAdd(&wcnt[w], 1); if (p < CAPW) cidx[w][p] = j + 3; }
  }
  const int cnt = wcnt[w];

  if (cnt > CAPW) {
    if (lane == 0) flags[row] = 1;
    return;
  }

  // exact sequential-k fmaf chains (bit-identical to the verified chain)
  for (int c = lane; c < cnt; c += 64) {
    const float4* ej4 = (const float4*)(e32 + (size_t)cidx[w][c] * DD);
    float a = 0.f;
    for (int k4 = 0; k4 < DD / 4; ++k4) {
      float4 vv = ej4[k4];
      const float* e = &er[w][k4 * 4];
      a = fmaf(e[0], vv.x, a);
      a = fmaf(e[1], vv.y, a);
      a = fmaf(e[2], vv.z, a);
      a = fmaf(e[3], vv.w, a);
    }
    cval[w][c] = a;
  }

  // stable top-31 by (exact desc, idx asc)
  for (int c = lane; c < cnt; c += 64) {
    float v = cval[w][c];
    int idx = cidx[w][c];
    int rank = 0;
    for (int c2 = 0; c2 < cnt; ++c2) {
      float v2 = cval[w][c2];
      if (v2 > v || (v2 == v && cidx[w][c2] < idx)) ++rank;
    }
    if (rank < TOPK) {
      kidx[w][rank] = idx;
      kval[w][rank] = fmaxf(v, 0.0f);
      atomicOr(&bmap[w][idx >> 6], 1ull << (idx & 63));
    }
  }

  // write the output row (0 or kept value)
  float4* Cw4 = (float4*)Crow;
  for (int it = 0; it < 32; ++it) {
    int j4 = (it * 64 + lane) * 4;
    float4 o = make_float4(0.f, 0.f, 0.f, 0.f);
    unsigned long long word = bmap[w][j4 >> 6];
    unsigned nib = (unsigned)((word >> (j4 & 63)) & 0xFull);
    if (nib) {
#pragma unroll
      for (int c = 0; c < 4; ++c)
        if ((nib >> c) & 1u) {
          int j = j4 + c;
          float val = 0.f;
          for (int s = 0; s < TOPK; ++s)
            if (kidx[w][s] == j) val = kval[w][s];
          ((float*)&o)[c] = val;
        }
    }
    Cw4[it * 64 + lane] = o;
  }
}

// ---------------------------------------------------------------------------
// Kernel D: exact cleanup for flagged rows (statistically never executes).
// ---------------------------------------------------------------------------
__global__ __launch_bounds__(256) void cleanup_kernel(
    float* __restrict__ C, const float* __restrict__ e32,
    const int* __restrict__ flags) {
  const int row = blockIdx.x;
  if (flags[row] == 0) return;
  const int tid = threadIdx.x;
  const int lane = tid & 63, wid = tid >> 6;

  __shared__ float sv[NN];
  __shared__ float er[DD];
  __shared__ unsigned long long wred[4];
  __shared__ int kidx[TOPK];
  __shared__ float kval[TOPK];

  {
    const float4* e4 = (const float4*)(e32 + (size_t)row * DD);
    if (tid < DD / 4) ((float4*)er)[tid] = e4[tid];
  }
  __syncthreads();

  for (int m = 0; m < NN / 256; ++m) {
    int j = m * 256 + tid;
    const float* ej = e32 + (size_t)j * DD;
    float a = 0.f;
    for (int k = 0; k < DD; k += 4) {
      float4 v = *(const float4*)&ej[k];
      a = fmaf(er[k], v.x, a);
      a = fmaf(er[k + 1], v.y, a);
      a = fmaf(er[k + 2], v.z, a);
      a = fmaf(er[k + 3], v.w, a);
    }
    sv[j] = a;
  }
  __syncthreads();

  for (int it = 0; it < TOPK; ++it) {
    float bv = -FLT_MAX;
    int bi = 0;
    for (int j = tid; j < NN; j += 256) {
      float v = sv[j];
      if (v > bv) { bv = v; bi = j; }
    }
    unsigned long long key =
        ((unsigned long long)ordmap(bv) << 32) | (unsigned)(NN - 1 - bi);
#pragma unroll
    for (int off = 32; off; off >>= 1) {
      unsigned long long o = __shfl_xor(key, off);
      if (o > key) key = o;
    }
    if (lane == 0) wred[wid] = key;
    __syncthreads();
    if (tid == 0) {
      unsigned long long k0 = wred[0];
      if (wred[1] > k0) k0 = wred[1];
      if (wred[2] > k0) k0 = wred[2];
      if (wred[3] > k0) k0 = wred[3];
      int idx = (NN - 1) - (int)(k0 & 0xFFFFFFFFu);
      kidx[it] = idx;
      kval[it] = sv[idx];
      sv[idx] = -FLT_MAX;
    }
    __syncthreads();
  }

  float4 z4 = make_float4(0.f, 0.f, 0.f, 0.f);
  float4* sv4 = (float4*)sv;
  for (int i = tid; i < NN / 4; i += 256) sv4[i] = z4;
  __syncthreads();
  if (tid < TOPK) sv[kidx[tid]] = fmaxf(kval[tid], 0.0f);
  __syncthreads();
  float4* Cw4 = (float4*)(C + (size_t)row * NN);
  for (int i = tid; i < NN / 4; i += 256) Cw4[i] = sv4[i];
}

// ---------------------------------------------------------------------------
extern "C" void kernel_launch(void* const* d_in, const int* in_sizes, int n_in,
                              void* d_out, int out_size, void* d_ws,
                              size_t ws_size, hipStream_t stream) {
  const float* f = (const float*)d_in[0];
  const float* W1 = (const float*)d_in[1];
  const float* W2 = (const float*)d_in[2];
  float* out = (float*)d_out;
  char* ws = (char*)d_ws;
  float* e32 = (float*)ws;                                     // 16 MiB
  unsigned short* Ehi = (unsigned short*)(ws + (size_t)NN * DD * 4);   // 8 MiB
  unsigned short* Elo = (unsigned short*)(ws + (size_t)NN * DD * 6);   // 8 MiB
  float* TM = (float*)(ws + (size_t)NN * DD * 8);              // 2 MiB
  int* flags = (int*)(ws + (size_t)NN * DD * 8 + (size_t)NN * 64 * 4);  // 32 KB

  emb_kernel<<<NN / 4, 256, 0, stream>>>(f, W1, W2, e32, Ehi, Elo, flags);
  dim3 g2(NN / 128, NN / 128);
  sim_mfma<<<g2, 256, 0, stream>>>(Ehi, Elo, out, TM);
  topk_kernel<<<NN / 4, 256, 0, stream>>>(out, e32, TM, flags);
  cleanup_kernel<<<NN, 256, 0, stream>>>(out, e32, flags);
}